// Round 6
// baseline (445.037 us; speedup 1.0000x reference)
//
#include <hip/hip_runtime.h>
#include <hip/hip_cooperative_groups.h>

namespace cg = cooperative_groups;

#define TPG   4096    // nodes per graph (T)
#define DIMD  128
#define NEG   0.2f
#define NTHR  256
#define COOP_BLK 512  // 2 blocks/CU — conservative co-residency

__device__ __forceinline__ int load_edge(const void* ei, int is64, long idx) {
  if (is64) return (int)((const long long*)ei)[idx];
  return ((const int*)ei)[idx];
}

__device__ __forceinline__ int aload(const int* p) {
  return __hip_atomic_load(p, __ATOMIC_RELAXED, __HIP_MEMORY_SCOPE_AGENT);
}

// int64/int32 layout vote (256 threads sample odd dwords)
__device__ __forceinline__ int detect64_block(const unsigned* __restrict__ ei) {
  __shared__ int s64;
  int t = threadIdx.x;
  if (t == 0) s64 = 1;
  __syncthreads();
  {
    unsigned v = ei[2 * t + 1];
    if (v != 0u) s64 = 0;     // benign race: all writers write 0
  }
  __syncthreads();
  return s64;
}

// ---------------- shared device bodies (used by fused + fallback) ----------
__device__ __forceinline__ void gemm_tile(
    int tile, int t, const float* __restrict__ x, const float* __restrict__ W,
    const float* __restrict__ atts, const float* __restrict__ attd,
    float* __restrict__ h, float* __restrict__ as_n, float* __restrict__ ad_n,
    float4 (*xs4)[33]) {
  const float4* x4 = (const float4*)x;
  int base = tile * 16;
  for (int i = t; i < 512; i += 256) xs4[i >> 5][i & 31] = x4[base * 32 + i];
  __syncthreads();

  int n_sub = t & 15, cgrp = t >> 4;
  int c0 = cgrp * 8;
  const float4* W4 = (const float4*)W;
  float acc[8];
#pragma unroll
  for (int k = 0; k < 8; ++k) acc[k] = 0.f;
  for (int db = 0; db < 32; db += 8) {
    float4 xa[8];
#pragma unroll
    for (int i = 0; i < 8; ++i) xa[i] = xs4[n_sub][db + i];
#pragma unroll
    for (int k = 0; k < 8; ++k) {
      const float4* wr = W4 + (c0 + k) * 32 + db;
      float a = acc[k];
#pragma unroll
      for (int i = 0; i < 8; ++i) {
        float4 w = wr[i];
        a = fmaf(xa[i].x, w.x, a);
        a = fmaf(xa[i].y, w.y, a);
        a = fmaf(xa[i].z, w.z, a);
        a = fmaf(xa[i].w, w.w, a);
      }
      acc[k] = a;
    }
  }
  int n = base + n_sub;
  float4* hp = (float4*)(h + ((size_t)n << 7) + c0);
  hp[0] = make_float4(acc[0], acc[1], acc[2], acc[3]);
  hp[1] = make_float4(acc[4], acc[5], acc[6], acc[7]);

  float ps = 0.f, pd = 0.f;
#pragma unroll
  for (int k = 0; k < 8; ++k) {
    ps = fmaf(acc[k], atts[c0 + k], ps);
    pd = fmaf(acc[k], attd[c0 + k], pd);
  }
  ps += __shfl_xor(ps, 16); ps += __shfl_xor(ps, 32);
  pd += __shfl_xor(pd, 16); pd += __shfl_xor(pd, 32);
  if ((t & 48) == 0) {
    as_n[(n << 2) + (t >> 6)] = ps;
    ad_n[(n << 2) + (t >> 6)] = pd;
  }
}

// flash softmax + aggregation for one node (one wave)
__device__ __forceinline__ void aggr_node(
    int n, int lane, int beg, int end, const int* __restrict__ esrc,
    const float* __restrict__ h, const float* __restrict__ as_n,
    const float* __restrict__ ad_n, const float* __restrict__ bias,
    float* __restrict__ out, int use_aload) {
  int tloc = n & (TPG - 1);
  int nodebase = n - tloc;
  int myh = lane >> 4;
  const float2* __restrict__ h2 = (const float2*)h;
  float adst = ad_n[(n << 2) + myh];

  float m, s;
  float2 acc;
  {
    float e = as_n[(n << 2) + myh] + adst;   // self-loop
    e = e > 0.f ? e : NEG * e;
    m = e; s = 1.f;
    acc = h2[((size_t)n << 6) + lane];
  }

  for (int j0 = beg; j0 < end; j0 += 8) {
    int sgk[8];
#pragma unroll
    for (int k = 0; k < 8; ++k) {
      int j = j0 + k;
      int jj = (j < end) ? j : (end - 1);
      int v = use_aload ? aload(&esrc[jj]) : esrc[jj];
      sgk[k] = (j < end) ? (nodebase + v) : n;
    }
    float ask[8];
#pragma unroll
    for (int k = 0; k < 8; ++k) ask[k] = as_n[(sgk[k] << 2) + myh];
    float2 hv[8];
#pragma unroll
    for (int k = 0; k < 8; ++k) hv[k] = h2[((size_t)sgk[k] << 6) + lane];
    float ek[8];
#pragma unroll
    for (int k = 0; k < 8; ++k) {
      float e = ask[k] + adst;
      e = e > 0.f ? e : NEG * e;
      ek[k] = (j0 + k < end) ? e : -1e30f;
    }
    float bm = ek[0];
#pragma unroll
    for (int k = 1; k < 8; ++k) bm = fmaxf(bm, ek[k]);
    float mn = fmaxf(m, bm);
    float r = __expf(m - mn);
    float ps = 0.f, px = 0.f, py = 0.f;
#pragma unroll
    for (int k = 0; k < 8; ++k) {
      float al = __expf(ek[k] - mn);
      ps += al;
      px = fmaf(al, hv[k].x, px);
      py = fmaf(al, hv[k].y, py);
    }
    acc.x = fmaf(acc.x, r, px);
    acc.y = fmaf(acc.y, r, py);
    s = fmaf(s, r, ps);
    m = mn;
  }

  float invs = 1.f / (s + 1e-16f);
  int c = lane << 1;
  const float2 bi = *(const float2*)(bias + c);
  float2 o;
  o.x = fmaf(acc.x, invs, bi.x);
  o.y = fmaf(acc.y, invs, bi.y);
  *(float2*)(out + ((size_t)n << 7) + c) = o;
}

// ===================== fused cooperative kernel =====================
__global__ __launch_bounds__(NTHR, 2) void k_fused(
    const float* __restrict__ x, const void* __restrict__ ei,
    const float* __restrict__ W, const float* __restrict__ atts,
    const float* __restrict__ attd, const float* __restrict__ bias,
    float* __restrict__ out, float* __restrict__ h,
    float* __restrict__ as_n, float* __restrict__ ad_n,
    int* __restrict__ counts, int* __restrict__ offs,
    int* __restrict__ cursor, int* __restrict__ esrc, int E, int N) {
  cg::grid_group grid = cg::this_grid();
  __shared__ float4 xs4[16][33];
  __shared__ int wsum[4];
  int t = threadIdx.x;
  int bid = blockIdx.x;
  int nb = gridDim.x;
  int is64 = detect64_block((const unsigned*)ei);

  // phase 0: zero counts + GEMM
  for (int i = bid * NTHR + t; i < TPG; i += nb * NTHR) counts[i] = 0;
  int ntile = N / 16;
  for (int tile = bid; tile < ntile; tile += nb) {
    gemm_tile(tile, t, x, W, atts, attd, h, as_n, ad_n, xs4);
    __syncthreads();
  }
  grid.sync();

  // phase 1: histogram of dst
  for (int e = bid * NTHR + t; e < E; e += nb * NTHR) {
    int dst = load_edge(ei, is64, (long)E + e);
    atomicAdd(&counts[dst], 1);
  }
  grid.sync();

  // phase 2: exclusive scan (block 0, 256 threads x 16)
  if (bid == 0) {
    int v[16]; int sum = 0;
#pragma unroll
    for (int i = 0; i < 16; ++i) { v[i] = aload(&counts[t * 16 + i]); sum += v[i]; }
    int lane = t & 63, w = t >> 6;
    int sc = sum;
#pragma unroll
    for (int off = 1; off < 64; off <<= 1) {
      int o = __shfl_up(sc, off);
      if (lane >= off) sc += o;
    }
    if (lane == 63) wsum[w] = sc;
    __syncthreads();
    int wo = 0;
    for (int i = 0; i < w; ++i) wo += wsum[i];
    int a = wo + sc - sum;
#pragma unroll
    for (int i = 0; i < 16; ++i) {
      offs[t * 16 + i] = a; cursor[t * 16 + i] = a; a += v[i];
    }
    if (t == 255) offs[4096] = a;
  }
  grid.sync();

  // phase 3: scatter src by dst
  for (int e = bid * NTHR + t; e < E; e += nb * NTHR) {
    int src = load_edge(ei, is64, e);
    int dst = load_edge(ei, is64, (long)E + e);
    int pos = atomicAdd(&cursor[dst], 1);
    esrc[pos] = src;
  }
  grid.sync();

  // phase 4: aggregation, XCD-pinned (graph g -> XCDs {2g,2g+1})
  {
    int wv = t >> 6, lane = t & 63;
    int xcd = bid & 7;
    int g = xcd >> 1, pairbit = xcd & 1;
    int lb = ((bid >> 3) << 1) | pairbit;          // local block in graph
    int blocks_per_graph = nb >> 2;                 // nb multiple of 8
    int waves_per_graph = blocks_per_graph << 2;
    int per_wave = TPG / waves_per_graph;           // nodes per wave
    int lw = (lb << 2) + wv;
    int n0 = (g << 12) + lw * per_wave;
    for (int i = 0; i < per_wave; ++i) {
      int n = __builtin_amdgcn_readfirstlane(n0 + i);
      int tloc = n & (TPG - 1);
      int beg = __builtin_amdgcn_readfirstlane(aload(&offs[tloc]));
      int end = __builtin_amdgcn_readfirstlane(aload(&offs[tloc + 1]));
      aggr_node(n, lane, beg, end, esrc, h, as_n, ad_n, bias, out, 1);
    }
  }
}

// ===================== fallback kernels (proven R2/R4 path) ================
__global__ __launch_bounds__(256) void k_gemm(
    const float* __restrict__ x, const float* __restrict__ W,
    const float* __restrict__ atts, const float* __restrict__ attd,
    float* __restrict__ h, float* __restrict__ as_n, float* __restrict__ ad_n,
    int* __restrict__ counts, int* __restrict__ done) {
  __shared__ float4 xs4[16][33];
  int t = threadIdx.x;
  if (blockIdx.x < 16) counts[(blockIdx.x << 8) + t] = 0;
  if (blockIdx.x == 16 && t == 0) *done = 0;
  gemm_tile(blockIdx.x, t, x, W, atts, attd, h, as_n, ad_n, xs4);
}

__global__ __launch_bounds__(256) void k_histscan(
    const void* __restrict__ ei, int* __restrict__ counts,
    int* __restrict__ offs, int* __restrict__ cursor,
    int* __restrict__ done, int E) {
  int is64 = detect64_block((const unsigned*)ei);
  int t = threadIdx.x;
  int e = blockIdx.x * 256 + t;
  if (e < E) {
    int dst = load_edge(ei, is64, (long)E + e);
    atomicAdd(&counts[dst], 1);
  }
  __syncthreads();
  __shared__ int lastFlag;
  if (t == 0) {
    __threadfence();
    int prev = atomicAdd(done, 1);
    lastFlag = (prev == (int)gridDim.x - 1);
  }
  __syncthreads();
  if (!lastFlag) return;

  int v[16]; int sum = 0;
#pragma unroll
  for (int i = 0; i < 16; ++i) { v[i] = aload(&counts[t * 16 + i]); sum += v[i]; }
  int lane = t & 63, w = t >> 6;
  int sc = sum;
#pragma unroll
  for (int off = 1; off < 64; off <<= 1) {
    int o = __shfl_up(sc, off);
    if (lane >= off) sc += o;
  }
  __shared__ int wsum[4];
  if (lane == 63) wsum[w] = sc;
  __syncthreads();
  int wo = 0;
  for (int i = 0; i < w; ++i) wo += wsum[i];
  int a = wo + sc - sum;
#pragma unroll
  for (int i = 0; i < 16; ++i) {
    offs[t * 16 + i] = a; cursor[t * 16 + i] = a; a += v[i];
  }
  if (t == 255) offs[4096] = a;
}

__global__ __launch_bounds__(256) void k_scatter(const void* __restrict__ ei,
                                                 int* __restrict__ cursor,
                                                 int* __restrict__ esrc, int E) {
  int is64 = detect64_block((const unsigned*)ei);
  int e = blockIdx.x * blockDim.x + threadIdx.x;
  if (e >= E) return;
  int src = load_edge(ei, is64, e);
  int dst = load_edge(ei, is64, (long)E + e);
  int pos = atomicAdd(&cursor[dst], 1);
  esrc[pos] = src;
}

__global__ __launch_bounds__(256) void k_aggr(
    const int* __restrict__ offs, const int* __restrict__ esrc,
    const float* __restrict__ h, const float* __restrict__ as_n,
    const float* __restrict__ ad_n, const float* __restrict__ bias,
    float* __restrict__ out) {
  int lane = threadIdx.x & 63;
  int n = __builtin_amdgcn_readfirstlane((blockIdx.x << 2) + (threadIdx.x >> 6));
  int tloc = n & (TPG - 1);
  int beg = __builtin_amdgcn_readfirstlane(offs[tloc]);
  int end = __builtin_amdgcn_readfirstlane(offs[tloc + 1]);
  aggr_node(n, lane, beg, end, esrc, h, as_n, ad_n, bias, out, 0);
}

// ---------------------------------------------------------------------- host
extern "C" void kernel_launch(void* const* d_in, const int* in_sizes, int n_in,
                              void* d_out, int out_size, void* d_ws, size_t ws_size,
                              hipStream_t stream) {
  const float* x    = (const float*)d_in[0];
  const void*  ei   = d_in[1];
  const float* W    = (const float*)d_in[2];
  const float* atts = (const float*)d_in[3];
  const float* attd = (const float*)d_in[4];
  const float* bias = (const float*)d_in[5];
  float* out = (float*)d_out;

  int N = in_sizes[0] / DIMD;   // 16384
  int E = in_sizes[1] / 2;      // 131072

  char* p = (char*)d_ws;
  float* h      = (float*)p; p += (size_t)N * DIMD * 4;
  float* as_n   = (float*)p; p += (size_t)N * 4 * 4;
  float* ad_n   = (float*)p; p += (size_t)N * 4 * 4;
  int*   counts = (int*)p;   p += (size_t)TPG * 4;
  int*   offs   = (int*)p;   p += (size_t)(TPG + 1) * 4;
  int*   cursor = (int*)p;   p += (size_t)TPG * 4;
  int*   esrc   = (int*)p;   p += (size_t)E * 4;
  int*   done   = (int*)p;   p += 4;

  // conservative cooperative grid: min(512, occupancy*256CU), multiple of 8
  int maxBpc = 0;
  hipError_t qerr = hipOccupancyMaxActiveBlocksPerMultiprocessor(
      &maxBpc, (const void*)k_fused, NTHR, 0);
  int grid = COOP_BLK;
  if (qerr == hipSuccess && maxBpc >= 1) {
    int cap = maxBpc * 256;
    if (cap < grid) grid = cap & ~7;      // keep multiple of 8 for XCD map
  }
  bool coop_ok = (grid >= 8);

  if (coop_ok) {
    void* args[] = {
      (void*)&x, (void*)&ei, (void*)&W, (void*)&atts, (void*)&attd, (void*)&bias,
      (void*)&out, (void*)&h, (void*)&as_n, (void*)&ad_n,
      (void*)&counts, (void*)&offs, (void*)&cursor, (void*)&esrc,
      (void*)&E, (void*)&N
    };
    hipError_t lerr = hipLaunchCooperativeKernel((const void*)k_fused,
                                                 dim3(grid), dim3(NTHR),
                                                 args, 0, stream);
    if (lerr == hipSuccess) return;
    (void)hipGetLastError();              // clear sticky error, fall back
  }

  // fallback: proven 4-kernel path
  k_gemm<<<N / 16, 256, 0, stream>>>(x, W, atts, attd, h, as_n, ad_n, counts, done);
  k_histscan<<<(E + 255) / 256, 256, 0, stream>>>(ei, counts, offs, cursor, done, E);
  k_scatter<<<(E + 255) / 256, 256, 0, stream>>>(ei, cursor, esrc, E);
  k_aggr<<<N / 4, 256, 0, stream>>>(offs, esrc, h, as_n, ad_n, bias, out);
}

// Round 7
// 155.626 us; speedup vs baseline: 2.8597x; 2.8597x over previous
//
#include <hip/hip_runtime.h>

#define TPG   4096    // nodes per graph (T)
#define DIMD  128
#define NEG   0.2f

__device__ __forceinline__ int load_edge(const void* ei, int is64, long idx) {
  if (is64) return (int)((const long long*)ei)[idx];
  return ((const int*)ei)[idx];
}

__device__ __forceinline__ int aload(const int* p) {
  return __hip_atomic_load(p, __ATOMIC_RELAXED, __HIP_MEMORY_SCOPE_AGENT);
}

// int64/int32 layout vote (256 threads sample odd dwords)
__device__ __forceinline__ int detect64_block(const unsigned* __restrict__ ei) {
  __shared__ int s64;
  int t = threadIdx.x;
  if (t == 0) s64 = 1;
  __syncthreads();
  {
    unsigned v = ei[2 * t + 1];
    if (v != 0u) s64 = 0;     // benign race: all writers write 0
  }
  __syncthreads();
  return s64;
}

// ------------------------------------------------- GEMM h = x*W^T + att dots
// block = 256 threads, 16 nodes/block; thread (n_sub=t&15, cgrp=t>>4) computes
// 8 channels. h stored as BF16 (halves aggr read traffic); att dots in fp32.
// Blocks 0..15 zero hist counters; block 16 zeroes done counter.
__global__ __launch_bounds__(256) void k_gemm(
    const float* __restrict__ x, const float* __restrict__ W,
    const float* __restrict__ atts, const float* __restrict__ attd,
    unsigned short* __restrict__ hbf, float* __restrict__ as_n,
    float* __restrict__ ad_n, int* __restrict__ counts, int* __restrict__ done) {
  __shared__ float4 xs4[16][33];   // +1 float4 pad
  int t = threadIdx.x;
  if (blockIdx.x < 16) counts[(blockIdx.x << 8) + t] = 0;
  if (blockIdx.x == 16 && t == 0) *done = 0;
  int base = blockIdx.x * 16;
  const float4* x4 = (const float4*)x;
  for (int i = t; i < 512; i += 256) xs4[i >> 5][i & 31] = x4[base * 32 + i];
  __syncthreads();

  int n_sub = t & 15, cgrp = t >> 4;
  int c0 = cgrp * 8;
  const float4* W4 = (const float4*)W;
  float acc[8];
#pragma unroll
  for (int k = 0; k < 8; ++k) acc[k] = 0.f;

  for (int db = 0; db < 32; db += 8) {
    float4 xa[8];
#pragma unroll
    for (int i = 0; i < 8; ++i) xa[i] = xs4[n_sub][db + i];
#pragma unroll
    for (int k = 0; k < 8; ++k) {
      const float4* wr = W4 + (c0 + k) * 32 + db;
      float a = acc[k];
#pragma unroll
      for (int i = 0; i < 8; ++i) {
        float4 w = wr[i];
        a = fmaf(xa[i].x, w.x, a);
        a = fmaf(xa[i].y, w.y, a);
        a = fmaf(xa[i].z, w.z, a);
        a = fmaf(xa[i].w, w.w, a);
      }
      acc[k] = a;
    }
  }

  int n = base + n_sub;
  // pack 8 channels to bf16 (RNE) -> one uint4 store (16B)
  uint4 pk;
  unsigned r[8];
#pragma unroll
  for (int k = 0; k < 8; ++k) {
    unsigned u = __float_as_uint(acc[k]);
    unsigned rnd = ((u >> 16) & 1u) + 0x7fffu;
    r[k] = (u + rnd) >> 16;                      // bf16 round-to-nearest-even
  }
  pk.x = r[0] | (r[1] << 16);
  pk.y = r[2] | (r[3] << 16);
  pk.z = r[4] | (r[5] << 16);
  pk.w = r[6] | (r[7] << 16);
  *(uint4*)(hbf + ((size_t)n << 7) + c0) = pk;

  float ps = 0.f, pd = 0.f;
#pragma unroll
  for (int k = 0; k < 8; ++k) {
    ps = fmaf(acc[k], atts[c0 + k], ps);
    pd = fmaf(acc[k], attd[c0 + k], pd);
  }
  ps += __shfl_xor(ps, 16); ps += __shfl_xor(ps, 32);
  pd += __shfl_xor(pd, 16); pd += __shfl_xor(pd, 32);
  if ((t & 48) == 0) {
    as_n[(n << 2) + (t >> 6)] = ps;
    ad_n[(n << 2) + (t >> 6)] = pd;
  }
}

// --------------------------------------- CSR: histogram + last-block scan
__global__ __launch_bounds__(256) void k_histscan(
    const void* __restrict__ ei, int* __restrict__ counts,
    int* __restrict__ offs, int* __restrict__ cursor,
    int* __restrict__ done, int E) {
  int is64 = detect64_block((const unsigned*)ei);
  int t = threadIdx.x;
  int e = blockIdx.x * 256 + t;
  if (e < E) {
    int dst = load_edge(ei, is64, (long)E + e);
    atomicAdd(&counts[dst], 1);
  }
  __syncthreads();
  __shared__ int lastFlag;
  if (t == 0) {
    __threadfence();
    int prev = atomicAdd(done, 1);
    lastFlag = (prev == (int)gridDim.x - 1);
  }
  __syncthreads();
  if (!lastFlag) return;

  int v[16]; int sum = 0;
#pragma unroll
  for (int i = 0; i < 16; ++i) { v[i] = aload(&counts[t * 16 + i]); sum += v[i]; }
  int lane = t & 63, w = t >> 6;
  int sc = sum;
#pragma unroll
  for (int off = 1; off < 64; off <<= 1) {
    int o = __shfl_up(sc, off);
    if (lane >= off) sc += o;
  }
  __shared__ int wsum[4];
  if (lane == 63) wsum[w] = sc;
  __syncthreads();
  int wo = 0;
  for (int i = 0; i < w; ++i) wo += wsum[i];
  int a = wo + sc - sum;
#pragma unroll
  for (int i = 0; i < 16; ++i) {
    offs[t * 16 + i] = a; cursor[t * 16 + i] = a; a += v[i];
  }
  if (t == 255) offs[4096] = a;
}

__global__ __launch_bounds__(256) void k_scatter(const void* __restrict__ ei,
                                                 int* __restrict__ cursor,
                                                 int* __restrict__ esrc, int E) {
  int is64 = detect64_block((const unsigned*)ei);
  int e = blockIdx.x * blockDim.x + threadIdx.x;
  if (e >= E) return;
  int src = load_edge(ei, is64, e);
  int dst = load_edge(ei, is64, (long)E + e);
  int pos = atomicAdd(&cursor[dst], 1);
  esrc[pos] = src;
}

// --------------------- flash softmax + aggregation, XCD-pinned, bf16 h -----
// 4096 blocks; xcd = bid&7 (round-robin dispatch assumption), graph g=xcd>>1:
// each XCD only gathers from its graph's 1MB bf16 h-slice -> L2-resident.
// One wave per node; lane owns channels {2l,2l+1} (one dword of bf16x2);
// head = lane>>4. Edge batches of 8: wave-uniform s_loads, 8 gathers in
// flight, branch-free online-softmax rescale. No atomics.
__global__ __launch_bounds__(256) void k_aggr(
    const int* __restrict__ offs, const int* __restrict__ esrc,
    const unsigned* __restrict__ h2, const float* __restrict__ as_n,
    const float* __restrict__ ad_n, const float* __restrict__ bias,
    float* __restrict__ out) {
  int bid = blockIdx.x;
  int wv = threadIdx.x >> 6;
  int lane = threadIdx.x & 63;
  int xcd = bid & 7;
  int g = xcd >> 1;
  int lb = ((bid >> 3) << 1) | (xcd & 1);     // 0..1023 within graph
  int nodebase = g << 12;
  int n = __builtin_amdgcn_readfirstlane(nodebase + (lb << 2) + wv);
  int tloc = n & (TPG - 1);
  int beg = __builtin_amdgcn_readfirstlane(offs[tloc]);
  int end = __builtin_amdgcn_readfirstlane(offs[tloc + 1]);

  int myh = lane >> 4;
  float adst = ad_n[(n << 2) + myh];

  float m, s;
  float ax, ay;
  {
    float e = as_n[(n << 2) + myh] + adst;    // self-loop
    e = e > 0.f ? e : NEG * e;
    m = e; s = 1.f;
    unsigned v = h2[((size_t)n << 6) + lane];
    ax = __uint_as_float(v << 16);
    ay = __uint_as_float(v & 0xffff0000u);
  }

  for (int j0 = beg; j0 < end; j0 += 8) {
    int sgk[8];
#pragma unroll
    for (int k = 0; k < 8; ++k) {
      int j = j0 + k;
      sgk[k] = (j < end) ? (nodebase + esrc[j]) : n;   // uniform -> s_load
    }
    unsigned hv[8];
#pragma unroll
    for (int k = 0; k < 8; ++k) hv[k] = h2[((size_t)sgk[k] << 6) + lane];
    float ask[8];
#pragma unroll
    for (int k = 0; k < 8; ++k) ask[k] = as_n[(sgk[k] << 2) + myh];
    float ek[8];
#pragma unroll
    for (int k = 0; k < 8; ++k) {
      float e = ask[k] + adst;
      e = e > 0.f ? e : NEG * e;
      ek[k] = (j0 + k < end) ? e : -1e30f;             // tail contributes 0
    }
    float bm = fmaxf(fmaxf(fmaxf(ek[0], ek[1]), fmaxf(ek[2], ek[3])),
                     fmaxf(fmaxf(ek[4], ek[5]), fmaxf(ek[6], ek[7])));
    float mn = fmaxf(m, bm);
    float r = __expf(m - mn);
    float ps = 0.f, px = 0.f, py = 0.f;
#pragma unroll
    for (int k = 0; k < 8; ++k) {
      float al = __expf(ek[k] - mn);
      ps += al;
      px = fmaf(al, __uint_as_float(hv[k] << 16), px);
      py = fmaf(al, __uint_as_float(hv[k] & 0xffff0000u), py);
    }
    ax = fmaf(ax, r, px);
    ay = fmaf(ay, r, py);
    s = fmaf(s, r, ps);
    m = mn;
  }

  float invs = 1.f / (s + 1e-16f);
  int c = lane << 1;
  const float2 bi = *(const float2*)(bias + c);
  float2 o;
  o.x = fmaf(ax, invs, bi.x);
  o.y = fmaf(ay, invs, bi.y);
  *(float2*)(out + ((size_t)n << 7) + c) = o;
}

// ---------------------------------------------------------------------- host
extern "C" void kernel_launch(void* const* d_in, const int* in_sizes, int n_in,
                              void* d_out, int out_size, void* d_ws, size_t ws_size,
                              hipStream_t stream) {
  const float* x    = (const float*)d_in[0];
  const void*  ei   = d_in[1];
  const float* W    = (const float*)d_in[2];
  const float* atts = (const float*)d_in[3];
  const float* attd = (const float*)d_in[4];
  const float* bias = (const float*)d_in[5];
  float* out = (float*)d_out;

  int N = in_sizes[0] / DIMD;   // 16384
  int E = in_sizes[1] / 2;      // 131072

  char* p = (char*)d_ws;
  unsigned short* hbf = (unsigned short*)p; p += (size_t)N * DIMD * 2;
  float* as_n   = (float*)p; p += (size_t)N * 4 * 4;
  float* ad_n   = (float*)p; p += (size_t)N * 4 * 4;
  int*   counts = (int*)p;   p += (size_t)TPG * 4;
  int*   offs   = (int*)p;   p += (size_t)(TPG + 1) * 4;
  int*   cursor = (int*)p;   p += (size_t)TPG * 4;
  int*   esrc   = (int*)p;   p += (size_t)E * 4;
  int*   done   = (int*)p;   p += 4;

  k_gemm<<<N / 16, 256, 0, stream>>>(x, W, atts, attd, hbf, as_n, ad_n, counts, done);
  k_histscan<<<(E + 255) / 256, 256, 0, stream>>>(ei, counts, offs, cursor, done, E);
  k_scatter<<<(E + 255) / 256, 256, 0, stream>>>(ei, cursor, esrc, E);
  k_aggr<<<N / 4, 256, 0, stream>>>(offs, esrc, (const unsigned*)hbf, as_n, ad_n, bias, out);
}